// Round 4
// baseline (607.910 us; speedup 1.0000x reference)
//
#include <hip/hip_runtime.h>

// Problem dims
#define B_  32
#define N_  1024
#define E_  1024
#define H_  8
#define D_  128
#define MID_ 64
#define NT_  32        // n-tiles for fused score+pool (32 rows each)
#define TR_  32        // rows per tile = N_/NT_
#define NS2_ 32        // n-splits for v2 pooling (32 rows each)

// All inputs are float32 (verified: threshold = 2%*max|ref| with no bf16 floor
// => _any_bf16 false). Output is float32 (reference returns jnp.float32).

// ---------------------------------------------------------------------------
// k_pre (fused): blocks [0,256): qkproj per (b,h); blocks [256,1280): v2 pool.
// ---------------------------------------------------------------------------
__global__ __launch_bounds__(256) void k_pre(
        const float* __restrict__ query, const float* __restrict__ Wq,
        const float* __restrict__ bq, const float* __restrict__ Wk,
        const float* __restrict__ bk, float* __restrict__ qk,
        float* __restrict__ qb,
        const float* __restrict__ value2, const int* __restrict__ mask,
        float* __restrict__ P2)
{
    const int t = threadIdx.x;

    __shared__ __align__(16) float qsh[E_];   // staged query[b], 4 KB
    __shared__ float Qs[D_];
    __shared__ float red[4];
    __shared__ int rows[N_ / NS2_];
    __shared__ int nrows;

    if (blockIdx.x < 256) {
        const int bh = blockIdx.x;
        const int b = bh >> 3, h = bh & 7;
        const int l = t & 63, w = t >> 6;       // 4 waves
        const int rg = l >> 4, cl = l & 15;     // 4 row-groups x 16 lanes

        // stage query[b]
        ((float4*)qsh)[t] = ((const float4*)(query + (size_t)b * E_))[t];
        __syncthreads();

        // phase A: Q[d] = query[b]·Wq_row(h*D+d) + bq, coalesced 16-lane rows
        const float4* qsh4 = (const float4*)qsh;
        float qbacc = 0.f;
        #pragma unroll 2
        for (int p = 0; p < 8; ++p) {
            const int d = p * 16 + w * 4 + rg;          // each d once
            const int row = h * D_ + d;
            const float4* wr = (const float4*)(Wq + (size_t)row * E_);
            float acc = 0.f;
            #pragma unroll 4
            for (int i = 0; i < 16; ++i) {
                float4 wv = wr[cl + i * 16];
                float4 qv = qsh4[cl + i * 16];
                acc += wv.x * qv.x + wv.y * qv.y + wv.z * qv.z + wv.w * qv.w;
            }
            #pragma unroll
            for (int off = 8; off; off >>= 1) acc += __shfl_xor(acc, off);
            if (cl == 0) {
                float q = acc + bq[row];
                Qs[d] = q;
                qbacc += q * bk[row];     // accumulated over the 8 passes
            }
        }
        // qb = sum_d Qs[d]*bk[row]: qbacc nonzero only on cl==0 lanes
        #pragma unroll
        for (int off = 32; off; off >>= 1) qbacc += __shfl_down(qbacc, off);
        if (l == 0) red[w] = qbacc;
        __syncthreads();
        if (t == 0) qb[bh] = red[0] + red[1] + red[2] + red[3];

        // phase B: qk row, thread owns 4 e's (coalesced float4 per d-iter)
        const int e0 = t * 4;
        float4 a = make_float4(0.f, 0.f, 0.f, 0.f);
        const float* wkb = Wk + (size_t)(h * D_) * E_ + e0;
        #pragma unroll 8
        for (int d = 0; d < D_; ++d) {
            float Qd = Qs[d];
            float4 wv = *(const float4*)(wkb + (size_t)d * E_);
            a.x += Qd * wv.x; a.y += Qd * wv.y; a.z += Qd * wv.z; a.w += Qd * wv.w;
        }
        *(float4*)(qk + (size_t)bh * E_ + e0) = a;
    } else {
        // ---- v2 pooling: P2[b,e] += sum_{n in split, mask=1} value2[b,n,e]
        const int idx = blockIdx.x - 256;
        const int b = idx & 31, ns = idx >> 5;
        const int e0 = t * 4;
        const int n0 = ns * (N_ / NS2_);   // 32 rows per split

        if (t == 0) nrows = 0;
        __syncthreads();
        if (t < N_ / NS2_) {
            if (mask[b * N_ + n0 + t]) {
                int i2 = atomicAdd(&nrows, 1);
                rows[i2] = t;
            }
        }
        __syncthreads();
        const int nr = nrows;

        float a0 = 0.f, a1 = 0.f, a2 = 0.f, a3 = 0.f;
        const float* vb = value2 + ((size_t)(b * N_ + n0)) * E_ + e0;
        #pragma unroll 4
        for (int i = 0; i < nr; ++i) {
            float4 v = *(const float4*)(vb + (size_t)rows[i] * E_);
            a0 += v.x; a1 += v.y; a2 += v.z; a3 += v.w;
        }
        float* dst = P2 + (size_t)b * E_ + e0;
        atomicAdd(dst + 0, a0); atomicAdd(dst + 1, a1);
        atomicAdd(dst + 2, a2); atomicAdd(dst + 3, a3);
    }
}

// ---------------------------------------------------------------------------
// K2 (fused score+pool): per (tile,b), 32-row tiles, all 8 heads per block.
//   NO qk LDS staging: qk[b] (32 KB, shared by the 32 same-b tile-blocks) is
//   read straight from L2 — LDS drops to ~1 KB, so occupancy is bound only by
//   grid (1024 blocks = 4/CU = 16 waves/CU) and VGPRs (launch_bounds 4 w/EU).
//   Key rows are disjoint across blocks: key read from HBM exactly once.
//   phase1: s[n,h] = (key[n]·qk[h] + qb[h]) / sqrt(D), register-prefetched
//           kf pipeline (4 HBM loads in flight during each FMA phase).
//   phase2: atomicAdd PP[b,h,e] += sum_n s[n,h]*key[n,e] (tile L2-hot)
// grid (NT_, B_), 256 threads
// ---------------------------------------------------------------------------
__global__ __launch_bounds__(256, 4) void k_scorepool(
        const float* __restrict__ key, const float* __restrict__ qk,
        const float* __restrict__ qb, float* __restrict__ PP,
        float* __restrict__ ssum)
{
    const int tile = blockIdx.x, b = blockIdx.y;
    const int t = threadIdx.x;
    const int c = t & 31, g = t >> 5;     // 8 groups of 32 lanes

    __shared__ __align__(16) float ssc[TR_][H_];   // 1 KB

    const float scale = 0.08838834764831845f;  // 1/sqrt(128)
    const float* keyb = key + ((size_t)b * N_ + (size_t)tile * TR_) * E_;
    const float4* qk4 = (const float4*)(qk + (size_t)b * H_ * E_);
    const float qbv = qb[b * 8 + (c & 7)];     // lane c==h uses qb[b,h]

    // group g owns rows g*4 .. g*4+3
    float acc[H_][4];
    #pragma unroll
    for (int h = 0; h < H_; ++h)
        #pragma unroll
        for (int j = 0; j < 4; ++j) acc[h][j] = 0.f;

    const float4* kr[4];
    #pragma unroll
    for (int j = 0; j < 4; ++j)
        kr[j] = (const float4*)(keyb + (size_t)(g * 4 + j) * E_);

    // software-pipelined: prefetch kf for i+1 while FMA-ing i
    float4 kf[4];
    #pragma unroll
    for (int j = 0; j < 4; ++j) kf[j] = kr[j][c];
    #pragma unroll
    for (int i = 0; i < 8; ++i) {
        float4 kn[4];
        if (i < 7) {
            #pragma unroll
            for (int j = 0; j < 4; ++j) kn[j] = kr[j][(i + 1) * 32 + c];
        }
        #pragma unroll
        for (int h = 0; h < H_; ++h) {
            float4 qf = qk4[h * 256 + i * 32 + c];   // L2-hot (shared by 32 blocks)
            #pragma unroll
            for (int j = 0; j < 4; ++j) {
                acc[h][j] += qf.x * kf[j].x + qf.y * kf[j].y
                           + qf.z * kf[j].z + qf.w * kf[j].w;
            }
        }
        if (i < 7) {
            #pragma unroll
            for (int j = 0; j < 4; ++j) kf[j] = kn[j];
        }
    }
    // butterfly allreduce over the 32 lanes of this group (offsets <32 never
    // cross the wave's group boundary at lane bit 5)
    #pragma unroll
    for (int off = 16; off; off >>= 1) {
        #pragma unroll
        for (int h = 0; h < H_; ++h)
            #pragma unroll
            for (int j = 0; j < 4; ++j)
                acc[h][j] += __shfl_xor(acc[h][j], off);
    }
    // lanes c<8 store s for h=c (compile-time indices only, no scratch)
    float tsum = 0.f;
    #pragma unroll
    for (int h = 0; h < H_; ++h) {
        if (c == h) {
            #pragma unroll
            for (int j = 0; j < 4; ++j) {
                float s = (acc[h][j] + qbv) * scale;
                ssc[g * 4 + j][h] = s;
                tsum += s;
            }
        }
    }
    if (c < H_) atomicAdd(&ssum[b * 8 + c], tsum);
    __syncthreads();

    // phase 2: thread owns 4 e's; loop tile's 32 rows (L2-hot re-read)
    {
        const int e0 = t * 4;
        float pacc[H_][4] = {};
        const float* kb = keyb + e0;
        #pragma unroll 4
        for (int n = 0; n < TR_; ++n) {
            float4 kv = *(const float4*)(kb + (size_t)n * E_);
            float4 s0 = *(const float4*)&ssc[n][0];
            float4 s1 = *(const float4*)&ssc[n][4];
            pacc[0][0] += s0.x * kv.x; pacc[0][1] += s0.x * kv.y;
            pacc[0][2] += s0.x * kv.z; pacc[0][3] += s0.x * kv.w;
            pacc[1][0] += s0.y * kv.x; pacc[1][1] += s0.y * kv.y;
            pacc[1][2] += s0.y * kv.z; pacc[1][3] += s0.y * kv.w;
            pacc[2][0] += s0.z * kv.x; pacc[2][1] += s0.z * kv.y;
            pacc[2][2] += s0.z * kv.z; pacc[2][3] += s0.z * kv.w;
            pacc[3][0] += s0.w * kv.x; pacc[3][1] += s0.w * kv.y;
            pacc[3][2] += s0.w * kv.z; pacc[3][3] += s0.w * kv.w;
            pacc[4][0] += s1.x * kv.x; pacc[4][1] += s1.x * kv.y;
            pacc[4][2] += s1.x * kv.z; pacc[4][3] += s1.x * kv.w;
            pacc[5][0] += s1.y * kv.x; pacc[5][1] += s1.y * kv.y;
            pacc[5][2] += s1.y * kv.z; pacc[5][3] += s1.y * kv.w;
            pacc[6][0] += s1.z * kv.x; pacc[6][1] += s1.z * kv.y;
            pacc[6][2] += s1.z * kv.z; pacc[6][3] += s1.z * kv.w;
            pacc[7][0] += s1.w * kv.x; pacc[7][1] += s1.w * kv.y;
            pacc[7][2] += s1.w * kv.z; pacc[7][3] += s1.w * kv.w;
        }
        #pragma unroll
        for (int h = 0; h < H_; ++h) {
            float* dst = PP + ((size_t)(b * H_) + h) * E_ + e0;
            atomicAdd(dst + 0, pacc[h][0]); atomicAdd(dst + 1, pacc[h][1]);
            atomicAdd(dst + 2, pacc[h][2]); atomicAdd(dst + 3, pacc[h][3]);
        }
    }
}

// ---------------------------------------------------------------------------
// k_att: heavy Wv dots, d-partitioned across blocks (no cross-d dependency
// here — the att->hv dependency lives in k_final).
//  attA[bh,d] = PP[b,h]·Wv_row(h*D+d);  attV[bh,d] = P2[b]·Wv_row(h*D+d)
// grid (4 dq, 256 bh), 256 threads -> 1024 blocks
// ---------------------------------------------------------------------------
__global__ __launch_bounds__(256) void k_att(
        const float* __restrict__ PP, const float* __restrict__ P2,
        const float* __restrict__ Wv,
        float* __restrict__ attA, float* __restrict__ attV)
{
    const int dq = blockIdx.x, bh = blockIdx.y;
    const int b = bh >> 3, h = bh & 7;
    const int t = threadIdx.x;
    const int l = t & 63, w = t >> 6;       // 4 waves
    const int rg = l >> 4, cl = l & 15;     // 4 row-groups x 16 lanes

    __shared__ __align__(16) float pooled[E_];
    __shared__ __align__(16) float pool2[E_];

    ((float4*)pooled)[t] = ((const float4*)(PP + ((size_t)(b * H_) + h) * E_))[t];
    ((float4*)pool2)[t]  = ((const float4*)(P2 + (size_t)b * E_))[t];
    __syncthreads();

    const float4* pooled4 = (const float4*)pooled;
    const float4* pool24  = (const float4*)pool2;
    #pragma unroll
    for (int p = 0; p < 2; ++p) {
        const int d = dq * 32 + p * 16 + w * 4 + rg;   // this block's 32 d's
        const float4* wvr = (const float4*)(Wv + (size_t)(h * D_ + d) * E_);
        float pA = 0.f, pV = 0.f;
        #pragma unroll 4
        for (int i = 0; i < 16; ++i) {
            float4 wv4 = wvr[cl + i * 16];
            float4 pa = pooled4[cl + i * 16];
            float4 pb = pool24[cl + i * 16];
            pA += wv4.x * pa.x + wv4.y * pa.y + wv4.z * pa.z + wv4.w * pa.w;
            pV += wv4.x * pb.x + wv4.y * pb.y + wv4.z * pb.z + wv4.w * pb.w;
        }
        #pragma unroll
        for (int off = 8; off; off >>= 1) {
            pA += __shfl_xor(pA, off);
            pV += __shfl_xor(pV, off);
        }
        if (cl == 0) {
            attA[(size_t)bh * D_ + d] = pA;
            attV[(size_t)bh * D_ + d] = pV;
        }
    }
}

// ---------------------------------------------------------------------------
// k_final (light epilogue). per (b,h), 128 threads (t = d)
//  att_d = attA + ssum*bv_d ; hv_m = relu(att·Wb_m + bb_m)
//  alphac_d = sigmoid(hv·Wl2_d + bl2_d) ; v2a_d = attV/cnt + bv_d
//  out = v1 * v2a * alphac
// ---------------------------------------------------------------------------
__global__ __launch_bounds__(128) void k_final(
        const float* __restrict__ attA, const float* __restrict__ attV,
        const float* __restrict__ ssumg, const int* __restrict__ mask,
        const float* __restrict__ bv, const float* __restrict__ Wb,
        const float* __restrict__ bb, const float* __restrict__ Wl2,
        const float* __restrict__ bl2, const float* __restrict__ value1,
        float* __restrict__ out)
{
    const int bh = blockIdx.x, b = bh >> 3, h = bh & 7;
    const int t = threadIdx.x;

    __shared__ float att[D_];
    __shared__ float hv[MID_];
    __shared__ float red2[2];
    __shared__ float cnt_s;

    int ci = 0;
    #pragma unroll
    for (int i = 0; i < 8; ++i) ci += mask[b * N_ + t + i * 128];
    float cf = (float)ci;
    #pragma unroll
    for (int off = 32; off; off >>= 1) cf += __shfl_down(cf, off);
    if ((t & 63) == 0) red2[t >> 6] = cf;

    const float ss = ssumg[bh];
    att[t] = attA[(size_t)bh * D_ + t] + ss * bv[h * D_ + t];
    __syncthreads();
    if (t == 0) cnt_s = red2[0] + red2[1];
    if (t < MID_) {
        float a = bb[t];
        #pragma unroll 4
        for (int d2 = 0; d2 < D_; ++d2) a += att[d2] * Wb[t * D_ + d2];
        hv[t] = fmaxf(a, 0.f);
    }
    __syncthreads();

    float z = bl2[t];
    #pragma unroll
    for (int m = 0; m < MID_; ++m) z += hv[m] * Wl2[t * MID_ + m];
    float alphac = 1.f / (1.f + expf(-z));
    const float bvd = bv[h * D_ + t];
    float v2a = attV[(size_t)bh * D_ + t] / cnt_s + bvd;
    out[(size_t)b * E_ + h * D_ + t] =
        value1[(size_t)b * E_ + h * D_ + t] * v2a * alphac;
}

// ---------------------------------------------------------------------------
extern "C" void kernel_launch(void* const* d_in, const int* in_sizes, int n_in,
                              void* d_out, int out_size, void* d_ws, size_t ws_size,
                              hipStream_t stream)
{
    const float* query  = (const float*)d_in[0];
    const float* key    = (const float*)d_in[1];
    const int*   mask   = (const int*)d_in[2];
    const float* value1 = (const float*)d_in[3];
    const float* value2 = (const float*)d_in[4];
    const float* Wq  = (const float*)d_in[5];
    const float* bq  = (const float*)d_in[6];
    const float* Wk  = (const float*)d_in[7];
    const float* bk  = (const float*)d_in[8];
    const float* Wv  = (const float*)d_in[9];
    const float* bv  = (const float*)d_in[10];
    const float* Wb  = (const float*)d_in[11];
    const float* bb  = (const float*)d_in[12];
    // d_in[13] = Wl, d_in[14] = bl: eliminated (softmax over identical values = mask/cnt)
    const float* Wl2 = (const float*)d_in[15];
    const float* bl2 = (const float*)d_in[16];
    float* out = (float*)d_out;

    // workspace layout (bytes), total ~2.4 MB
    char* ws = (char*)d_ws;
    const size_t OFF_P2 = (size_t)B_ * H_ * E_ * 4;     // PP: 1 MB
    const size_t OFF_SS = OFF_P2 + (size_t)B_ * E_ * 4; // P2: 128 KB
    const size_t OFF_QB = OFF_SS + 1024;                // ssum: 1 KB
    const size_t OFF_QK = OFF_QB + 1024;                // qb: 1 KB
    const size_t OFF_AA = OFF_QK + (size_t)B_ * H_ * E_ * 4;  // qk: 1 MB
    const size_t OFF_AV = OFF_AA + (size_t)B_ * H_ * D_ * 4;  // attA: 128 KB
    float* PP   = (float*)(ws);
    float* P2   = (float*)(ws + OFF_P2);
    float* ssum = (float*)(ws + OFF_SS);
    float* qb   = (float*)(ws + OFF_QB);
    float* qk   = (float*)(ws + OFF_QK);
    float* attA = (float*)(ws + OFF_AA);
    float* attV = (float*)(ws + OFF_AV);                // attV: 128 KB

    // zero the atomic-accumulated region (PP, P2, ssum); stream-ordered, capture-safe
    hipMemsetAsync(d_ws, 0, OFF_QB, stream);

    hipLaunchKernelGGL(k_pre, dim3(256 + NS2_ * B_), dim3(256), 0, stream,
                       query, Wq, bq, Wk, bk, qk, qb, value2, mask, P2);
    hipLaunchKernelGGL(k_scorepool, dim3(NT_, B_), dim3(256), 0, stream,
                       key, qk, qb, PP, ssum);
    hipLaunchKernelGGL(k_att, dim3(4, B_ * H_), dim3(256), 0, stream,
                       PP, P2, Wv, attA, attV);
    hipLaunchKernelGGL(k_final, dim3(B_ * H_), dim3(128), 0, stream,
                       attA, attV, ssum, mask, bv, Wb, bb, Wl2, bl2, value1, out);
}

// Round 5
// 499.894 us; speedup vs baseline: 1.2161x; 1.2161x over previous
//
#include <hip/hip_runtime.h>

// Problem dims
#define B_  32
#define N_  1024
#define E_  1024
#define H_  8
#define D_  128
#define MID_ 64
#define NT_  32        // n-tiles for fused score+pool (32 rows each)
#define TR_  32        // rows per tile = N_/NT_
#define NS2_ 16        // n-splits for v2 pooling (64 rows each)

// All inputs are float32 (verified: threshold = 2%*max|ref| with no bf16 floor
// => _any_bf16 false). Output is float32 (reference returns jnp.float32).

// ---------------------------------------------------------------------------
// k_pre (fused, 1024 threads = 16 waves/block):
//   blocks [0,256): qkproj per (b,h); blocks [256,768): v2 pooling.
//   qkproj was 4 waves at 1 block/CU (12.5% occ) — now 16 waves + 4-way
//   d-split phase B with LDS partial reduction.
// ---------------------------------------------------------------------------
__global__ __launch_bounds__(1024, 4) void k_pre(
        const float* __restrict__ query, const float* __restrict__ Wq,
        const float* __restrict__ bq, const float* __restrict__ Wk,
        const float* __restrict__ bk, float* __restrict__ qk,
        float* __restrict__ qb,
        const float* __restrict__ value2, const int* __restrict__ mask,
        float* __restrict__ P2)
{
    const int t = threadIdx.x;

    __shared__ __align__(16) float qsh[E_];      // staged query[b], 4 KB
    __shared__ float Qs[D_];
    __shared__ __align__(16) float part[4 * E_]; // 16 KB partials (both paths)
    __shared__ float redq[16];
    __shared__ int rows[N_ / NS2_];
    __shared__ int nrows;

    if (blockIdx.x < 256) {
        // ---- qkproj: Q = query[b]·Wq_h^T + bq ; qb = Q·bk_h ; qk = Q·Wk_h
        const int bh = blockIdx.x;
        const int b = bh >> 3, h = bh & 7;

        if (t < 256)
            ((float4*)qsh)[t] = ((const float4*)(query + (size_t)b * E_))[t];
        __syncthreads();

        // phase A: 8 lanes per d-row (128 rows x 8 lanes = 1024 threads)
        {
            const int d = t >> 3, cl = t & 7;
            const int row = h * D_ + d;
            const float4* wr = (const float4*)(Wq + (size_t)row * E_);
            const float4* qsh4 = (const float4*)qsh;
            float acc = 0.f;
            #pragma unroll 4
            for (int i = 0; i < 32; ++i) {
                float4 w = wr[cl + i * 8];
                float4 q = qsh4[cl + i * 8];
                acc += w.x * q.x + w.y * q.y + w.z * q.z + w.w * q.w;
            }
            #pragma unroll
            for (int off = 4; off; off >>= 1) acc += __shfl_xor(acc, off);
            float qp = 0.f;
            if (cl == 0) {
                float qv = acc + bq[row];
                Qs[d] = qv;
                qp = qv * bk[row];
            }
            // full-wave reduce (non-cl0 lanes carry 0)
            #pragma unroll
            for (int off = 32; off; off >>= 1) qp += __shfl_down(qp, off);
            if ((t & 63) == 0) redq[t >> 6] = qp;
        }
        __syncthreads();
        if (t == 0) {
            float s = 0.f;
            #pragma unroll
            for (int i = 0; i < 16; ++i) s += redq[i];
            qb[bh] = s;
        }

        // phase B: qk[e] = sum_d Qs[d]*Wk[h*D+d, e]; 4-way d-split
        {
            const int dq = t >> 8, e4 = t & 255;   // dq uniform per wave
            const float* wkb = Wk + (size_t)(h * D_ + dq * 32) * E_;
            float4 a = make_float4(0.f, 0.f, 0.f, 0.f);
            #pragma unroll 8
            for (int dd = 0; dd < 32; ++dd) {
                float Qd = Qs[dq * 32 + dd];
                float4 w = ((const float4*)(wkb + (size_t)dd * E_))[e4];
                a.x += Qd * w.x; a.y += Qd * w.y;
                a.z += Qd * w.z; a.w += Qd * w.w;
            }
            ((float4*)part)[dq * 256 + e4] = a;
        }
        __syncthreads();
        if (t < 256) {
            float4 p0 = ((float4*)part)[t];
            float4 p1 = ((float4*)part)[256 + t];
            float4 p2 = ((float4*)part)[512 + t];
            float4 p3 = ((float4*)part)[768 + t];
            float4 s = make_float4(p0.x + p1.x + p2.x + p3.x,
                                   p0.y + p1.y + p2.y + p3.y,
                                   p0.z + p1.z + p2.z + p3.z,
                                   p0.w + p1.w + p2.w + p3.w);
            ((float4*)(qk + (size_t)bh * E_))[t] = s;
        }
    } else {
        // ---- v2 pooling: P2[b,e] += sum_{n in split, mask=1} value2[b,n,e]
        const int idx = blockIdx.x - 256;
        const int b = idx & 31, ns = idx >> 5;    // 16 splits of 64 rows
        const int n0 = ns * (N_ / NS2_);

        if (t == 0) nrows = 0;
        __syncthreads();
        if (t < N_ / NS2_) {
            if (mask[b * N_ + n0 + t]) {
                int i2 = atomicAdd(&nrows, 1);
                rows[i2] = t;
            }
        }
        __syncthreads();
        const int nr = nrows;

        const int e4 = t & 255, rq = t >> 8;      // 4-way row interleave
        const float* vb = value2 + ((size_t)(b * N_ + n0)) * E_;
        float4 a = make_float4(0.f, 0.f, 0.f, 0.f);
        #pragma unroll 2
        for (int i = rq; i < nr; i += 4) {
            float4 v = ((const float4*)(vb + (size_t)rows[i] * E_))[e4];
            a.x += v.x; a.y += v.y; a.z += v.z; a.w += v.w;
        }
        ((float4*)part)[rq * 256 + e4] = a;
        __syncthreads();
        if (t < 256) {
            float4 p0 = ((float4*)part)[t];
            float4 p1 = ((float4*)part)[256 + t];
            float4 p2 = ((float4*)part)[512 + t];
            float4 p3 = ((float4*)part)[768 + t];
            float* dst = P2 + (size_t)b * E_ + t * 4;
            atomicAdd(dst + 0, p0.x + p1.x + p2.x + p3.x);
            atomicAdd(dst + 1, p0.y + p1.y + p2.y + p3.y);
            atomicAdd(dst + 2, p0.z + p1.z + p2.z + p3.z);
            atomicAdd(dst + 3, p0.w + p1.w + p2.w + p3.w);
        }
    }
}

// ---------------------------------------------------------------------------
// K2 (fused score+pool): per (tile,b), 32-row tiles, all 8 heads per block.
//   qk[b] staged in LDS (32 KB) — kills the qf L2/HBM re-fetch of round 4.
//   phase1: s[n,h] = (key[n]·qk[h] + qb[h]) / sqrt(D); 32-lane groups own
//           4 rows, depth-2 register prefetch on key.
//   phase2: PLAIN float4 stores into PPpart[b,h,tile,e] — NO atomics.
//           (round-4 lesson: 8M 32-writer atomicAdds = 454 MB of HBM RMW.)
// grid (NT_, B_) = 1024 blocks, 256 thr; LDS 33 KB -> 4 blocks/CU.
// ---------------------------------------------------------------------------
__global__ __launch_bounds__(256, 4) void k_scorepool(
        const float* __restrict__ key, const float* __restrict__ qk,
        const float* __restrict__ qb, float* __restrict__ PPpart,
        float* __restrict__ ssum)
{
    const int tile = blockIdx.x, b = blockIdx.y;
    const int t = threadIdx.x;
    const int c = t & 31, g = t >> 5;     // 8 groups of 32 lanes

    __shared__ __align__(16) float qks[H_ * E_];   // 32 KB
    __shared__ __align__(16) float ssc[TR_][H_];   // 1 KB

    // stage qk[b] into LDS, coalesced float4
    {
        const float4* src = (const float4*)(qk + (size_t)b * H_ * E_);
        float4* dst = (float4*)qks;
        #pragma unroll
        for (int k = 0; k < 8; ++k) dst[t + k * 256] = src[t + k * 256];
    }
    __syncthreads();

    const float scale = 0.08838834764831845f;  // 1/sqrt(128)
    const float* keyb = key + ((size_t)b * N_ + (size_t)tile * TR_) * E_;
    const float4* qks4 = (const float4*)qks;
    const float qbv = qb[b * 8 + (c & 7)];     // lane c==h uses qb[b,h]

    // group g owns rows g*4 .. g*4+3
    float acc[H_][4];
    #pragma unroll
    for (int h = 0; h < H_; ++h)
        #pragma unroll
        for (int j = 0; j < 4; ++j) acc[h][j] = 0.f;

    const float4* kr[4];
    #pragma unroll
    for (int j = 0; j < 4; ++j)
        kr[j] = (const float4*)(keyb + (size_t)(g * 4 + j) * E_);

    // depth-2 software pipeline: 8-12 key loads in flight per lane
    float4 kf[4], kn[4];
    #pragma unroll
    for (int j = 0; j < 4; ++j) { kf[j] = kr[j][c]; kn[j] = kr[j][32 + c]; }
    #pragma unroll
    for (int i = 0; i < 8; ++i) {
        float4 k2[4];
        if (i < 6) {
            #pragma unroll
            for (int j = 0; j < 4; ++j) k2[j] = kr[j][(i + 2) * 32 + c];
        }
        #pragma unroll
        for (int h = 0; h < H_; ++h) {
            float4 qf = qks4[h * 256 + i * 32 + c];
            #pragma unroll
            for (int j = 0; j < 4; ++j) {
                acc[h][j] += qf.x * kf[j].x + qf.y * kf[j].y
                           + qf.z * kf[j].z + qf.w * kf[j].w;
            }
        }
        #pragma unroll
        for (int j = 0; j < 4; ++j) {
            kf[j] = kn[j];
            if (i < 6) kn[j] = k2[j];
        }
    }
    // butterfly allreduce over the 32 lanes of this group
    #pragma unroll
    for (int off = 16; off; off >>= 1) {
        #pragma unroll
        for (int h = 0; h < H_; ++h)
            #pragma unroll
            for (int j = 0; j < 4; ++j)
                acc[h][j] += __shfl_xor(acc[h][j], off);
    }
    // lanes c<8 store s for h=c (compile-time indices only, no scratch)
    float tsum = 0.f;
    #pragma unroll
    for (int h = 0; h < H_; ++h) {
        if (c == h) {
            #pragma unroll
            for (int j = 0; j < 4; ++j) {
                float s = (acc[h][j] + qbv) * scale;
                ssc[g * 4 + j][h] = s;
                tsum += s;
            }
        }
    }
    if (c < H_) atomicAdd(&ssum[b * 8 + c], tsum);
    __syncthreads();

    // phase 2: thread owns 4 e's; loop tile's 32 rows (same-block L2-hot)
    {
        const int e0 = t * 4;
        float pacc[H_][4] = {};
        const float* kb = keyb + e0;
        #pragma unroll 4
        for (int n = 0; n < TR_; ++n) {
            float4 kv = *(const float4*)(kb + (size_t)n * E_);
            float4 s0 = *(const float4*)&ssc[n][0];
            float4 s1 = *(const float4*)&ssc[n][4];
            pacc[0][0] += s0.x * kv.x; pacc[0][1] += s0.x * kv.y;
            pacc[0][2] += s0.x * kv.z; pacc[0][3] += s0.x * kv.w;
            pacc[1][0] += s0.y * kv.x; pacc[1][1] += s0.y * kv.y;
            pacc[1][2] += s0.y * kv.z; pacc[1][3] += s0.y * kv.w;
            pacc[2][0] += s0.z * kv.x; pacc[2][1] += s0.z * kv.y;
            pacc[2][2] += s0.z * kv.z; pacc[2][3] += s0.z * kv.w;
            pacc[3][0] += s0.w * kv.x; pacc[3][1] += s0.w * kv.y;
            pacc[3][2] += s0.w * kv.z; pacc[3][3] += s0.w * kv.w;
            pacc[4][0] += s1.x * kv.x; pacc[4][1] += s1.x * kv.y;
            pacc[4][2] += s1.x * kv.z; pacc[4][3] += s1.x * kv.w;
            pacc[5][0] += s1.y * kv.x; pacc[5][1] += s1.y * kv.y;
            pacc[5][2] += s1.y * kv.z; pacc[5][3] += s1.y * kv.w;
            pacc[6][0] += s1.z * kv.x; pacc[6][1] += s1.z * kv.y;
            pacc[6][2] += s1.z * kv.z; pacc[6][3] += s1.z * kv.w;
            pacc[7][0] += s1.w * kv.x; pacc[7][1] += s1.w * kv.y;
            pacc[7][2] += s1.w * kv.z; pacc[7][3] += s1.w * kv.w;
        }
        // plain stores: each (b,h,tile,e) written exactly once
        #pragma unroll
        for (int h = 0; h < H_; ++h) {
            float* dst = PPpart + (((size_t)(b * H_ + h)) * NT_ + tile) * E_ + e0;
            *(float4*)dst = make_float4(pacc[h][0], pacc[h][1],
                                        pacc[h][2], pacc[h][3]);
        }
    }
}

// ---------------------------------------------------------------------------
// k_att: reduce the 32 PPpart partials into pooled (LDS), then heavy Wv dots,
// d-partitioned across blocks.
//  attA[bh,d] = pooled·Wv_row(h*D+d);  attV[bh,d] = P2[b]·Wv_row(h*D+d)
// grid (4 dq, 256 bh), 256 threads -> 1024 blocks
// ---------------------------------------------------------------------------
__global__ __launch_bounds__(256, 4) void k_att(
        const float* __restrict__ PPpart, const float* __restrict__ P2,
        const float* __restrict__ Wv,
        float* __restrict__ attA, float* __restrict__ attV)
{
    const int dq = blockIdx.x, bh = blockIdx.y;
    const int b = bh >> 3, h = bh & 7;
    const int t = threadIdx.x;
    const int l = t & 63, w = t >> 6;       // 4 waves
    const int rg = l >> 4, cl = l & 15;     // 4 row-groups x 16 lanes

    __shared__ __align__(16) float pooled[E_];
    __shared__ __align__(16) float pool2[E_];

    // stage pooled = sum over 32 tile-partials (32 indep 1KB-strided loads)
    {
        const float4* pp = (const float4*)(PPpart + (size_t)(b * H_ + h) * NT_ * E_);
        float4 s = make_float4(0.f, 0.f, 0.f, 0.f);
        #pragma unroll 8
        for (int tl = 0; tl < NT_; ++tl) {
            float4 v = pp[tl * 256 + t];
            s.x += v.x; s.y += v.y; s.z += v.z; s.w += v.w;
        }
        ((float4*)pooled)[t] = s;
        ((float4*)pool2)[t]  = ((const float4*)(P2 + (size_t)b * E_))[t];
    }
    __syncthreads();

    const float4* pooled4 = (const float4*)pooled;
    const float4* pool24  = (const float4*)pool2;
    #pragma unroll
    for (int p = 0; p < 2; ++p) {
        const int d = dq * 32 + p * 16 + w * 4 + rg;   // this block's 32 d's
        const float4* wvr = (const float4*)(Wv + (size_t)(h * D_ + d) * E_);
        float pA = 0.f, pV = 0.f;
        #pragma unroll 4
        for (int i = 0; i < 16; ++i) {
            float4 wv4 = wvr[cl + i * 16];
            float4 pa = pooled4[cl + i * 16];
            float4 pb = pool24[cl + i * 16];
            pA += wv4.x * pa.x + wv4.y * pa.y + wv4.z * pa.z + wv4.w * pa.w;
            pV += wv4.x * pb.x + wv4.y * pb.y + wv4.z * pb.z + wv4.w * pb.w;
        }
        #pragma unroll
        for (int off = 8; off; off >>= 1) {
            pA += __shfl_xor(pA, off);
            pV += __shfl_xor(pV, off);
        }
        if (cl == 0) {
            attA[(size_t)bh * D_ + d] = pA;
            attV[(size_t)bh * D_ + d] = pV;
        }
    }
}

// ---------------------------------------------------------------------------
// k_final (light epilogue). per (b,h), 128 threads (t = d)
//  att_d = attA + ssum*bv_d ; hv_m = relu(att·Wb_m + bb_m)
//  alphac_d = sigmoid(hv·Wl2_d + bl2_d) ; v2a_d = attV/cnt + bv_d
//  out = v1 * v2a * alphac
// ---------------------------------------------------------------------------
__global__ __launch_bounds__(128) void k_final(
        const float* __restrict__ attA, const float* __restrict__ attV,
        const float* __restrict__ ssumg, const int* __restrict__ mask,
        const float* __restrict__ bv, const float* __restrict__ Wb,
        const float* __restrict__ bb, const float* __restrict__ Wl2,
        const float* __restrict__ bl2, const float* __restrict__ value1,
        float* __restrict__ out)
{
    const int bh = blockIdx.x, b = bh >> 3, h = bh & 7;
    const int t = threadIdx.x;

    __shared__ float att[D_];
    __shared__ float hv[MID_];
    __shared__ float red2[2];
    __shared__ float cnt_s;

    int ci = 0;
    #pragma unroll
    for (int i = 0; i < 8; ++i) ci += mask[b * N_ + t + i * 128];
    float cf = (float)ci;
    #pragma unroll
    for (int off = 32; off; off >>= 1) cf += __shfl_down(cf, off);
    if ((t & 63) == 0) red2[t >> 6] = cf;

    const float ss = ssumg[bh];
    att[t] = attA[(size_t)bh * D_ + t] + ss * bv[h * D_ + t];
    __syncthreads();
    if (t == 0) cnt_s = red2[0] + red2[1];
    if (t < MID_) {
        float a = bb[t];
        #pragma unroll 4
        for (int d2 = 0; d2 < D_; ++d2) a += att[d2] * Wb[t * D_ + d2];
        hv[t] = fmaxf(a, 0.f);
    }
    __syncthreads();

    float z = bl2[t];
    #pragma unroll
    for (int m = 0; m < MID_; ++m) z += hv[m] * Wl2[t * MID_ + m];
    float alphac = 1.f / (1.f + expf(-z));
    const float bvd = bv[h * D_ + t];
    float v2a = attV[(size_t)bh * D_ + t] / cnt_s + bvd;
    out[(size_t)b * E_ + h * D_ + t] =
        value1[(size_t)b * E_ + h * D_ + t] * v2a * alphac;
}

// ---------------------------------------------------------------------------
extern "C" void kernel_launch(void* const* d_in, const int* in_sizes, int n_in,
                              void* d_out, int out_size, void* d_ws, size_t ws_size,
                              hipStream_t stream)
{
    const float* query  = (const float*)d_in[0];
    const float* key    = (const float*)d_in[1];
    const int*   mask   = (const int*)d_in[2];
    const float* value1 = (const float*)d_in[3];
    const float* value2 = (const float*)d_in[4];
    const float* Wq  = (const float*)d_in[5];
    const float* bq  = (const float*)d_in[6];
    const float* Wk  = (const float*)d_in[7];
    const float* bk  = (const float*)d_in[8];
    const float* Wv  = (const float*)d_in[9];
    const float* bv  = (const float*)d_in[10];
    const float* Wb  = (const float*)d_in[11];
    const float* bb  = (const float*)d_in[12];
    // d_in[13] = Wl, d_in[14] = bl: eliminated (softmax over identical values = mask/cnt)
    const float* Wl2 = (const float*)d_in[15];
    const float* bl2 = (const float*)d_in[16];
    float* out = (float*)d_out;

    // workspace layout (bytes), total ~35 MB
    char* ws = (char*)d_ws;
    const size_t SZ_PPP = (size_t)B_ * H_ * NT_ * E_ * 4;   // PPpart: 32 MB
    const size_t OFF_P2 = SZ_PPP;
    const size_t OFF_SS = OFF_P2 + (size_t)B_ * E_ * 4;     // P2: 128 KB
    const size_t OFF_QB = OFF_SS + 1024;                    // ssum: 1 KB
    const size_t OFF_QK = OFF_QB + 1024;                    // qb: 1 KB
    const size_t OFF_AA = OFF_QK + (size_t)B_ * H_ * E_ * 4;  // qk: 1 MB
    const size_t OFF_AV = OFF_AA + (size_t)B_ * H_ * D_ * 4;  // attA: 128 KB
    float* PPpart = (float*)(ws);
    float* P2   = (float*)(ws + OFF_P2);
    float* ssum = (float*)(ws + OFF_SS);
    float* qb   = (float*)(ws + OFF_QB);
    float* qk   = (float*)(ws + OFF_QK);
    float* attA = (float*)(ws + OFF_AA);
    float* attV = (float*)(ws + OFF_AV);                    // attV: 128 KB

    // zero only the atomic-accumulated region (P2 + ssum); PPpart is
    // fully overwritten by plain stores. stream-ordered, capture-safe
    hipMemsetAsync(ws + OFF_P2, 0, (size_t)B_ * E_ * 4 + 1024, stream);

    hipLaunchKernelGGL(k_pre, dim3(256 + NS2_ * B_), dim3(1024), 0, stream,
                       query, Wq, bq, Wk, bk, qk, qb, value2, mask, P2);
    hipLaunchKernelGGL(k_scorepool, dim3(NT_, B_), dim3(256), 0, stream,
                       key, qk, qb, PPpart, ssum);
    hipLaunchKernelGGL(k_att, dim3(4, B_ * H_), dim3(256), 0, stream,
                       PPpart, P2, Wv, attA, attV);
    hipLaunchKernelGGL(k_final, dim3(B_ * H_), dim3(128), 0, stream,
                       attA, attV, ssum, mask, bv, Wb, bb, Wl2, bl2, value1, out);
}

// Round 6
// 392.433 us; speedup vs baseline: 1.5491x; 1.2738x over previous
//
#include <hip/hip_runtime.h>

// Problem dims
#define B_  32
#define N_  1024
#define E_  1024
#define H_  8
#define D_  128
#define MID_ 64
#define NT_  32        // n-tiles for fused score+pool (32 rows each)
#define TR_  32        // rows per tile = N_/NT_
#define NS2_ 16        // n-splits for v2 pooling (64 rows each)

// All inputs are float32 (verified: threshold = 2%*max|ref| with no bf16 floor
// => _any_bf16 false). Output is float32 (reference returns jnp.float32).

// Journal (counter-backed lessons):
//  R3: never scale occupancy by replaying the same stream (FETCH doubled).
//  R4: never scale same-destination atomic writers (WRITE 454 MB of RMW).
//  R5: VGPR_Count=64 on a kernel with >64 live regs = spill to scratch
//      (≈300 MB of phantom HBM write traffic); phase-2 "L2-hot" re-reads
//      miss when resident tile footprint (16 MB/XCD) >> 4 MB L2.
//  => R6: single pass over key; register budget designed to ~115 VGPRs.

// ---------------------------------------------------------------------------
// k_pre (fused, 1024 threads = 16 waves/block):
//   blocks [0,256): qkproj per (b,h); blocks [256,768): v2 pooling.
// ---------------------------------------------------------------------------
__global__ __launch_bounds__(1024, 4) void k_pre(
        const float* __restrict__ query, const float* __restrict__ Wq,
        const float* __restrict__ bq, const float* __restrict__ Wk,
        const float* __restrict__ bk, float* __restrict__ qk,
        float* __restrict__ qb,
        const float* __restrict__ value2, const int* __restrict__ mask,
        float* __restrict__ P2)
{
    const int t = threadIdx.x;

    __shared__ __align__(16) float qsh[E_];      // staged query[b], 4 KB
    __shared__ float Qs[D_];
    __shared__ __align__(16) float part[4 * E_]; // 16 KB partials (both paths)
    __shared__ float redq[16];
    __shared__ int rows[N_ / NS2_];
    __shared__ int nrows;

    if (blockIdx.x < 256) {
        // ---- qkproj: Q = query[b]·Wq_h^T + bq ; qb = Q·bk_h ; qk = Q·Wk_h
        const int bh = blockIdx.x;
        const int b = bh >> 3, h = bh & 7;

        if (t < 256)
            ((float4*)qsh)[t] = ((const float4*)(query + (size_t)b * E_))[t];
        __syncthreads();

        // phase A: 8 lanes per d-row (128 rows x 8 lanes = 1024 threads)
        {
            const int d = t >> 3, cl = t & 7;
            const int row = h * D_ + d;
            const float4* wr = (const float4*)(Wq + (size_t)row * E_);
            const float4* qsh4 = (const float4*)qsh;
            float acc = 0.f;
            #pragma unroll 4
            for (int i = 0; i < 32; ++i) {
                float4 w = wr[cl + i * 8];
                float4 q = qsh4[cl + i * 8];
                acc += w.x * q.x + w.y * q.y + w.z * q.z + w.w * q.w;
            }
            #pragma unroll
            for (int off = 4; off; off >>= 1) acc += __shfl_xor(acc, off);
            float qp = 0.f;
            if (cl == 0) {
                float qv = acc + bq[row];
                Qs[d] = qv;
                qp = qv * bk[row];
            }
            // full-wave reduce (non-cl0 lanes carry 0)
            #pragma unroll
            for (int off = 32; off; off >>= 1) qp += __shfl_down(qp, off);
            if ((t & 63) == 0) redq[t >> 6] = qp;
        }
        __syncthreads();
        if (t == 0) {
            float s = 0.f;
            #pragma unroll
            for (int i = 0; i < 16; ++i) s += redq[i];
            qb[bh] = s;
        }

        // phase B: qk[e] = sum_d Qs[d]*Wk[h*D+d, e]; 4-way d-split
        {
            const int dq = t >> 8, e4 = t & 255;   // dq uniform per wave
            const float* wkb = Wk + (size_t)(h * D_ + dq * 32) * E_;
            float4 a = make_float4(0.f, 0.f, 0.f, 0.f);
            #pragma unroll 8
            for (int dd = 0; dd < 32; ++dd) {
                float Qd = Qs[dq * 32 + dd];
                float4 w = ((const float4*)(wkb + (size_t)dd * E_))[e4];
                a.x += Qd * w.x; a.y += Qd * w.y;
                a.z += Qd * w.z; a.w += Qd * w.w;
            }
            ((float4*)part)[dq * 256 + e4] = a;
        }
        __syncthreads();
        if (t < 256) {
            float4 p0 = ((float4*)part)[t];
            float4 p1 = ((float4*)part)[256 + t];
            float4 p2 = ((float4*)part)[512 + t];
            float4 p3 = ((float4*)part)[768 + t];
            float4 s = make_float4(p0.x + p1.x + p2.x + p3.x,
                                   p0.y + p1.y + p2.y + p3.y,
                                   p0.z + p1.z + p2.z + p3.z,
                                   p0.w + p1.w + p2.w + p3.w);
            ((float4*)(qk + (size_t)bh * E_))[t] = s;
        }
    } else {
        // ---- v2 pooling: P2[b,e] += sum_{n in split, mask=1} value2[b,n,e]
        const int idx = blockIdx.x - 256;
        const int b = idx & 31, ns = idx >> 5;    // 16 splits of 64 rows
        const int n0 = ns * (N_ / NS2_);

        if (t == 0) nrows = 0;
        __syncthreads();
        if (t < N_ / NS2_) {
            if (mask[b * N_ + n0 + t]) {
                int i2 = atomicAdd(&nrows, 1);
                rows[i2] = t;
            }
        }
        __syncthreads();
        const int nr = nrows;

        const int e4 = t & 255, rq = t >> 8;      // 4-way row interleave
        const float* vb = value2 + ((size_t)(b * N_ + n0)) * E_;
        float4 a = make_float4(0.f, 0.f, 0.f, 0.f);
        #pragma unroll 2
        for (int i = rq; i < nr; i += 4) {
            float4 v = ((const float4*)(vb + (size_t)rows[i] * E_))[e4];
            a.x += v.x; a.y += v.y; a.z += v.z; a.w += v.w;
        }
        ((float4*)part)[rq * 256 + e4] = a;
        __syncthreads();
        if (t < 256) {
            float4 p0 = ((float4*)part)[t];
            float4 p1 = ((float4*)part)[256 + t];
            float4 p2 = ((float4*)part)[512 + t];
            float4 p3 = ((float4*)part)[768 + t];
            float* dst = P2 + (size_t)b * E_ + t * 4;
            atomicAdd(dst + 0, p0.x + p1.x + p2.x + p3.x);
            atomicAdd(dst + 1, p0.y + p1.y + p2.y + p3.y);
            atomicAdd(dst + 2, p0.z + p1.z + p2.z + p3.z);
            atomicAdd(dst + 3, p0.w + p1.w + p2.w + p3.w);
        }
    }
}

// ---------------------------------------------------------------------------
// K2 single-pass score+pool: per (tile,b), 32-row tiles.
//   Wave w owns e-range [w*256,(w+1)*256); lane holds qk e-chunk for all 8
//   heads in regs (32 VGPR, loaded once). Per 4-row sub-tile:
//     dots: p[h] = kv·qkr[h]; 6-step shfl_xor wave allreduce; wave partials
//           finalized across 4 waves via 512B LDS -> s[n,h]
//     outer: pacc[h] += s[n,h]*kv (SAME kv regs — key read exactly once)
//   kv for next sub-tile prefetched during the barrier/finalize window.
//   Writes: PPpart plain stores (32 KB/block), 8 ssum atomics/block.
//   Register budget: qkr 32 + kv 16 + kn 16 + pacc 32 + temps ≈ 115 < 128.
// grid (NT_, B_) = 1024 blocks, 256 thr, ~1 KB LDS.
// ---------------------------------------------------------------------------
__global__ __launch_bounds__(256, 4) void k_scorepool(
        const float* __restrict__ key, const float* __restrict__ qk,
        const float* __restrict__ qb, float* __restrict__ PPpart,
        float* __restrict__ ssum)
{
    const int tile = blockIdx.x, b = blockIdx.y;
    const int t = threadIdx.x;
    const int w = t >> 6, l = t & 63;
    const int ei = (w << 6) + l;              // float4 index in [0,256)

    __shared__ __align__(16) float part[4][4][8];   // [wave][r][h], 512 B
    __shared__ __align__(16) float sfin[4][8];      // [r][h], 128 B

    const float scale = 0.08838834764831845f;  // 1/sqrt(128)
    const float* keyb = key + ((size_t)b * N_ + (size_t)tile * TR_) * E_;
    const float qbv = (t < 32) ? qb[b * 8 + (t & 7)] : 0.f;

    // qk fragments: 8 heads x float4 at this lane's e-chunk (read once)
    float4 qkr[8];
    #pragma unroll
    for (int h = 0; h < H_; ++h)
        qkr[h] = ((const float4*)(qk + (size_t)(b * 8 + h) * E_))[ei];

    float4 pacc[8];
    #pragma unroll
    for (int h = 0; h < 8; ++h) pacc[h] = make_float4(0.f, 0.f, 0.f, 0.f);

    float ts = 0.f;                           // finalize-thread accumulator

    float4 kv[4];
    #pragma unroll
    for (int r = 0; r < 4; ++r)
        kv[r] = ((const float4*)(keyb + (size_t)r * E_))[ei];

    for (int st = 0; st < 8; ++st) {
        // --- dots for this sub-tile's 4 rows
        #pragma unroll
        for (int r = 0; r < 4; ++r) {
            float p[8];
            #pragma unroll
            for (int h = 0; h < 8; ++h)
                p[h] = qkr[h].x * kv[r].x + qkr[h].y * kv[r].y
                     + qkr[h].z * kv[r].z + qkr[h].w * kv[r].w;
            #pragma unroll
            for (int off = 32; off; off >>= 1) {
                #pragma unroll
                for (int h = 0; h < 8; ++h)
                    p[h] += __shfl_xor(p[h], off);
            }
            if (l == 0) {
                *(float4*)&part[w][r][0] = make_float4(p[0], p[1], p[2], p[3]);
                *(float4*)&part[w][r][4] = make_float4(p[4], p[5], p[6], p[7]);
            }
        }
        // --- prefetch next sub-tile's rows (latency hidden by barriers)
        float4 kn[4];
        if (st < 7) {
            #pragma unroll
            for (int r = 0; r < 4; ++r)
                kn[r] = ((const float4*)(keyb
                            + (size_t)((st + 1) * 4 + r) * E_))[ei];
        }
        __syncthreads();
        // --- finalize s across the 4 waves (32 threads: r=t>>3, h=t&7)
        if (t < 32) {
            const int r = t >> 3, h = t & 7;
            float s = (part[0][r][h] + part[1][r][h]
                     + part[2][r][h] + part[3][r][h] + qbv) * scale;
            sfin[r][h] = s;
            ts += s;
        }
        __syncthreads();
        // --- outer product with the SAME kv registers
        #pragma unroll
        for (int r = 0; r < 4; ++r) {
            const float4 k4 = kv[r];
            const float4 sA = *(const float4*)&sfin[r][0];
            const float4 sB = *(const float4*)&sfin[r][4];
            pacc[0].x += sA.x * k4.x; pacc[0].y += sA.x * k4.y;
            pacc[0].z += sA.x * k4.z; pacc[0].w += sA.x * k4.w;
            pacc[1].x += sA.y * k4.x; pacc[1].y += sA.y * k4.y;
            pacc[1].z += sA.y * k4.z; pacc[1].w += sA.y * k4.w;
            pacc[2].x += sA.z * k4.x; pacc[2].y += sA.z * k4.y;
            pacc[2].z += sA.z * k4.z; pacc[2].w += sA.z * k4.w;
            pacc[3].x += sA.w * k4.x; pacc[3].y += sA.w * k4.y;
            pacc[3].z += sA.w * k4.z; pacc[3].w += sA.w * k4.w;
            pacc[4].x += sB.x * k4.x; pacc[4].y += sB.x * k4.y;
            pacc[4].z += sB.x * k4.z; pacc[4].w += sB.x * k4.w;
            pacc[5].x += sB.y * k4.x; pacc[5].y += sB.y * k4.y;
            pacc[5].z += sB.y * k4.z; pacc[5].w += sB.y * k4.w;
            pacc[6].x += sB.z * k4.x; pacc[6].y += sB.z * k4.y;
            pacc[6].z += sB.z * k4.z; pacc[6].w += sB.z * k4.w;
            pacc[7].x += sB.w * k4.x; pacc[7].y += sB.w * k4.y;
            pacc[7].z += sB.w * k4.z; pacc[7].w += sB.w * k4.w;
        }
        #pragma unroll
        for (int r = 0; r < 4; ++r) kv[r] = kn[r];
    }

    // --- ssum: finalize threads hold per-(r,h) tile sums; fold r, 8 atomics
    if (t < 32) {
        float v = ts;
        v += __shfl_xor(v, 8);
        v += __shfl_xor(v, 16);
        if (l < 8) atomicAdd(&ssum[b * 8 + l], v);
    }

    // --- PPpart write: one plain float4 store per (h, e-chunk)
    #pragma unroll
    for (int h = 0; h < 8; ++h) {
        ((float4*)(PPpart
            + (((size_t)(b * H_ + h)) * NT_ + tile) * E_))[ei] = pacc[h];
    }
}

// ---------------------------------------------------------------------------
// k_att: reduce the 32 PPpart partials into pooled (LDS), then heavy Wv dots,
// d-partitioned across blocks.
//  attA[bh,d] = pooled·Wv_row(h*D+d);  attV[bh,d] = P2[b]·Wv_row(h*D+d)
// grid (4 dq, 256 bh), 256 threads -> 1024 blocks
// ---------------------------------------------------------------------------
__global__ __launch_bounds__(256, 4) void k_att(
        const float* __restrict__ PPpart, const float* __restrict__ P2,
        const float* __restrict__ Wv,
        float* __restrict__ attA, float* __restrict__ attV)
{
    const int dq = blockIdx.x, bh = blockIdx.y;
    const int b = bh >> 3, h = bh & 7;
    const int t = threadIdx.x;
    const int l = t & 63, w = t >> 6;       // 4 waves
    const int rg = l >> 4, cl = l & 15;     // 4 row-groups x 16 lanes

    __shared__ __align__(16) float pooled[E_];
    __shared__ __align__(16) float pool2[E_];

    // stage pooled = sum over 32 tile-partials (32 indep 1KB-strided loads)
    {
        const float4* pp = (const float4*)(PPpart + (size_t)(b * H_ + h) * NT_ * E_);
        float4 s = make_float4(0.f, 0.f, 0.f, 0.f);
        #pragma unroll 8
        for (int tl = 0; tl < NT_; ++tl) {
            float4 v = pp[tl * 256 + t];
            s.x += v.x; s.y += v.y; s.z += v.z; s.w += v.w;
        }
        ((float4*)pooled)[t] = s;
        ((float4*)pool2)[t]  = ((const float4*)(P2 + (size_t)b * E_))[t];
    }
    __syncthreads();

    const float4* pooled4 = (const float4*)pooled;
    const float4* pool24  = (const float4*)pool2;
    #pragma unroll
    for (int p = 0; p < 2; ++p) {
        const int d = dq * 32 + p * 16 + w * 4 + rg;   // this block's 32 d's
        const float4* wvr = (const float4*)(Wv + (size_t)(h * D_ + d) * E_);
        float pA = 0.f, pV = 0.f;
        #pragma unroll 4
        for (int i = 0; i < 16; ++i) {
            float4 wv4 = wvr[cl + i * 16];
            float4 pa = pooled4[cl + i * 16];
            float4 pb = pool24[cl + i * 16];
            pA += wv4.x * pa.x + wv4.y * pa.y + wv4.z * pa.z + wv4.w * pa.w;
            pV += wv4.x * pb.x + wv4.y * pb.y + wv4.z * pb.z + wv4.w * pb.w;
        }
        #pragma unroll
        for (int off = 8; off; off >>= 1) {
            pA += __shfl_xor(pA, off);
            pV += __shfl_xor(pV, off);
        }
        if (cl == 0) {
            attA[(size_t)bh * D_ + d] = pA;
            attV[(size_t)bh * D_ + d] = pV;
        }
    }
}

// ---------------------------------------------------------------------------
// k_final (light epilogue). per (b,h), 128 threads (t = d)
//  att_d = attA + ssum*bv_d ; hv_m = relu(att·Wb_m + bb_m)
//  alphac_d = sigmoid(hv·Wl2_d + bl2_d) ; v2a_d = attV/cnt + bv_d
//  out = v1 * v2a * alphac
// ---------------------------------------------------------------------------
__global__ __launch_bounds__(128) void k_final(
        const float* __restrict__ attA, const float* __restrict__ attV,
        const float* __restrict__ ssumg, const int* __restrict__ mask,
        const float* __restrict__ bv, const float* __restrict__ Wb,
        const float* __restrict__ bb, const float* __restrict__ Wl2,
        const float* __restrict__ bl2, const float* __restrict__ value1,
        float* __restrict__ out)
{
    const int bh = blockIdx.x, b = bh >> 3, h = bh & 7;
    const int t = threadIdx.x;

    __shared__ float att[D_];
    __shared__ float hv[MID_];
    __shared__ float red2[2];
    __shared__ float cnt_s;

    int ci = 0;
    #pragma unroll
    for (int i = 0; i < 8; ++i) ci += mask[b * N_ + t + i * 128];
    float cf = (float)ci;
    #pragma unroll
    for (int off = 32; off; off >>= 1) cf += __shfl_down(cf, off);
    if ((t & 63) == 0) red2[t >> 6] = cf;

    const float ss = ssumg[bh];
    att[t] = attA[(size_t)bh * D_ + t] + ss * bv[h * D_ + t];
    __syncthreads();
    if (t == 0) cnt_s = red2[0] + red2[1];
    if (t < MID_) {
        float a = bb[t];
        #pragma unroll 4
        for (int d2 = 0; d2 < D_; ++d2) a += att[d2] * Wb[t * D_ + d2];
        hv[t] = fmaxf(a, 0.f);
    }
    __syncthreads();

    float z = bl2[t];
    #pragma unroll
    for (int m = 0; m < MID_; ++m) z += hv[m] * Wl2[t * MID_ + m];
    float alphac = 1.f / (1.f + expf(-z));
    const float bvd = bv[h * D_ + t];
    float v2a = attV[(size_t)bh * D_ + t] / cnt_s + bvd;
    out[(size_t)b * E_ + h * D_ + t] =
        value1[(size_t)b * E_ + h * D_ + t] * v2a * alphac;
}

// ---------------------------------------------------------------------------
extern "C" void kernel_launch(void* const* d_in, const int* in_sizes, int n_in,
                              void* d_out, int out_size, void* d_ws, size_t ws_size,
                              hipStream_t stream)
{
    const float* query  = (const float*)d_in[0];
    const float* key    = (const float*)d_in[1];
    const int*   mask   = (const int*)d_in[2];
    const float* value1 = (const float*)d_in[3];
    const float* value2 = (const float*)d_in[4];
    const float* Wq  = (const float*)d_in[5];
    const float* bq  = (const float*)d_in[6];
    const float* Wk  = (const float*)d_in[7];
    const float* bk  = (const float*)d_in[8];
    const float* Wv  = (const float*)d_in[9];
    const float* bv  = (const float*)d_in[10];
    const float* Wb  = (const float*)d_in[11];
    const float* bb  = (const float*)d_in[12];
    // d_in[13] = Wl, d_in[14] = bl: eliminated (softmax over identical values = mask/cnt)
    const float* Wl2 = (const float*)d_in[15];
    const float* bl2 = (const float*)d_in[16];
    float* out = (float*)d_out;

    // workspace layout (bytes), total ~35 MB
    char* ws = (char*)d_ws;
    const size_t SZ_PPP = (size_t)B_ * H_ * NT_ * E_ * 4;   // PPpart: 32 MB
    const size_t OFF_P2 = SZ_PPP;
    const size_t OFF_SS = OFF_P2 + (size_t)B_ * E_ * 4;     // P2: 128 KB
    const size_t OFF_QB = OFF_SS + 1024;                    // ssum: 1 KB
    const size_t OFF_QK = OFF_QB + 1024;                    // qb: 1 KB
    const size_t OFF_AA = OFF_QK + (size_t)B_ * H_ * E_ * 4;  // qk: 1 MB
    const size_t OFF_AV = OFF_AA + (size_t)B_ * H_ * D_ * 4;  // attA: 128 KB
    float* PPpart = (float*)(ws);
    float* P2   = (float*)(ws + OFF_P2);
    float* ssum = (float*)(ws + OFF_SS);
    float* qb   = (float*)(ws + OFF_QB);
    float* qk   = (float*)(ws + OFF_QK);
    float* attA = (float*)(ws + OFF_AA);
    float* attV = (float*)(ws + OFF_AV);                    // attV: 128 KB

    // zero only the atomic-accumulated region (P2 + ssum); PPpart is
    // fully overwritten by plain stores. stream-ordered, capture-safe
    hipMemsetAsync(ws + OFF_P2, 0, (size_t)B_ * E_ * 4 + 1024, stream);

    hipLaunchKernelGGL(k_pre, dim3(256 + NS2_ * B_), dim3(1024), 0, stream,
                       query, Wq, bq, Wk, bk, qk, qb, value2, mask, P2);
    hipLaunchKernelGGL(k_scorepool, dim3(NT_, B_), dim3(256), 0, stream,
                       key, qk, qb, PPpart, ssum);
    hipLaunchKernelGGL(k_att, dim3(4, B_ * H_), dim3(256), 0, stream,
                       PPpart, P2, Wv, attA, attV);
    hipLaunchKernelGGL(k_final, dim3(B_ * H_), dim3(128), 0, stream,
                       attA, attV, ssum, mask, bv, Wb, bb, Wl2, bl2, value1, out);
}

// Round 7
// 372.279 us; speedup vs baseline: 1.6329x; 1.0541x over previous
//
#include <hip/hip_runtime.h>

// Problem dims
#define B_  32
#define N_  1024
#define E_  1024
#define H_  8
#define D_  128
#define MID_ 64
#define NT_  32        // n-tiles for fused score+pool (32 rows each)
#define TR_  32        // rows per tile = N_/NT_
#define NS2_ 16        // n-splits for v2 pooling (64 rows each)

// All inputs are float32 (verified: threshold = 2%*max|ref| with no bf16 floor
// => _any_bf16 false). Output is float32 (reference returns jnp.float32).

// Journal (counter-backed lessons):
//  R3: never scale occupancy by replaying the same stream (FETCH doubled).
//  R4: never scale same-destination atomic writers (WRITE 454 MB of RMW).
//  R5: VGPR_Count=64 on a register-hungry kernel = spill to scratch
//      (~300 MB phantom writes); "L2-hot" re-reads miss when resident
//      footprint (16 MB/XCD) >> 4 MB L2.
//  R6: __launch_bounds__(X, 4) pushes the allocator to the 8-waves/EU
//      VGPR=64 target and it spills to get there (R4/R5/R6 all show the
//      64-cap signature; R1-R3 plain bounds allocated 44-88 freely).
//      Also: k_att re-read PPpart 4x (R3's lesson applied to my own code).
//  => R7: plain launch_bounds everywhere; k_red pre-reduces PPpart once.

// ---------------------------------------------------------------------------
// k_pre (fused, 1024 threads = 16 waves/block):
//   blocks [0,256): qkproj per (b,h); blocks [256,768): v2 pooling.
// ---------------------------------------------------------------------------
__global__ __launch_bounds__(1024) void k_pre(
        const float* __restrict__ query, const float* __restrict__ Wq,
        const float* __restrict__ bq, const float* __restrict__ Wk,
        const float* __restrict__ bk, float* __restrict__ qk,
        float* __restrict__ qb,
        const float* __restrict__ value2, const int* __restrict__ mask,
        float* __restrict__ P2)
{
    const int t = threadIdx.x;

    __shared__ __align__(16) float qsh[E_];      // staged query[b], 4 KB
    __shared__ float Qs[D_];
    __shared__ __align__(16) float part[4 * E_]; // 16 KB partials (both paths)
    __shared__ float redq[16];
    __shared__ int rows[N_ / NS2_];
    __shared__ int nrows;

    if (blockIdx.x < 256) {
        // ---- qkproj: Q = query[b]·Wq_h^T + bq ; qb = Q·bk_h ; qk = Q·Wk_h
        const int bh = blockIdx.x;
        const int b = bh >> 3, h = bh & 7;

        if (t < 256)
            ((float4*)qsh)[t] = ((const float4*)(query + (size_t)b * E_))[t];
        __syncthreads();

        // phase A: 8 lanes per d-row (128 rows x 8 lanes = 1024 threads)
        {
            const int d = t >> 3, cl = t & 7;
            const int row = h * D_ + d;
            const float4* wr = (const float4*)(Wq + (size_t)row * E_);
            const float4* qsh4 = (const float4*)qsh;
            float acc = 0.f;
            #pragma unroll 4
            for (int i = 0; i < 32; ++i) {
                float4 w = wr[cl + i * 8];
                float4 q = qsh4[cl + i * 8];
                acc += w.x * q.x + w.y * q.y + w.z * q.z + w.w * q.w;
            }
            #pragma unroll
            for (int off = 4; off; off >>= 1) acc += __shfl_xor(acc, off);
            float qp = 0.f;
            if (cl == 0) {
                float qv = acc + bq[row];
                Qs[d] = qv;
                qp = qv * bk[row];
            }
            // full-wave reduce (non-cl0 lanes carry 0)
            #pragma unroll
            for (int off = 32; off; off >>= 1) qp += __shfl_down(qp, off);
            if ((t & 63) == 0) redq[t >> 6] = qp;
        }
        __syncthreads();
        if (t == 0) {
            float s = 0.f;
            #pragma unroll
            for (int i = 0; i < 16; ++i) s += redq[i];
            qb[bh] = s;
        }

        // phase B: qk[e] = sum_d Qs[d]*Wk[h*D+d, e]; 4-way d-split
        {
            const int dq = t >> 8, e4 = t & 255;   // dq uniform per wave
            const float* wkb = Wk + (size_t)(h * D_ + dq * 32) * E_;
            float4 a = make_float4(0.f, 0.f, 0.f, 0.f);
            #pragma unroll 8
            for (int dd = 0; dd < 32; ++dd) {
                float Qd = Qs[dq * 32 + dd];
                float4 w = ((const float4*)(wkb + (size_t)dd * E_))[e4];
                a.x += Qd * w.x; a.y += Qd * w.y;
                a.z += Qd * w.z; a.w += Qd * w.w;
            }
            ((float4*)part)[dq * 256 + e4] = a;
        }
        __syncthreads();
        if (t < 256) {
            float4 p0 = ((float4*)part)[t];
            float4 p1 = ((float4*)part)[256 + t];
            float4 p2 = ((float4*)part)[512 + t];
            float4 p3 = ((float4*)part)[768 + t];
            float4 s = make_float4(p0.x + p1.x + p2.x + p3.x,
                                   p0.y + p1.y + p2.y + p3.y,
                                   p0.z + p1.z + p2.z + p3.z,
                                   p0.w + p1.w + p2.w + p3.w);
            ((float4*)(qk + (size_t)bh * E_))[t] = s;
        }
    } else {
        // ---- v2 pooling: P2[b,e] += sum_{n in split, mask=1} value2[b,n,e]
        const int idx = blockIdx.x - 256;
        const int b = idx & 31, ns = idx >> 5;    // 16 splits of 64 rows
        const int n0 = ns * (N_ / NS2_);

        if (t == 0) nrows = 0;
        __syncthreads();
        if (t < N_ / NS2_) {
            if (mask[b * N_ + n0 + t]) {
                int i2 = atomicAdd(&nrows, 1);
                rows[i2] = t;
            }
        }
        __syncthreads();
        const int nr = nrows;

        const int e4 = t & 255, rq = t >> 8;      // 4-way row interleave
        const float* vb = value2 + ((size_t)(b * N_ + n0)) * E_;
        float4 a = make_float4(0.f, 0.f, 0.f, 0.f);
        #pragma unroll 2
        for (int i = rq; i < nr; i += 4) {
            float4 v = ((const float4*)(vb + (size_t)rows[i] * E_))[e4];
            a.x += v.x; a.y += v.y; a.z += v.z; a.w += v.w;
        }
        ((float4*)part)[rq * 256 + e4] = a;
        __syncthreads();
        if (t < 256) {
            float4 p0 = ((float4*)part)[t];
            float4 p1 = ((float4*)part)[256 + t];
            float4 p2 = ((float4*)part)[512 + t];
            float4 p3 = ((float4*)part)[768 + t];
            float* dst = P2 + (size_t)b * E_ + t * 4;
            atomicAdd(dst + 0, p0.x + p1.x + p2.x + p3.x);
            atomicAdd(dst + 1, p0.y + p1.y + p2.y + p3.y);
            atomicAdd(dst + 2, p0.z + p1.z + p2.z + p3.z);
            atomicAdd(dst + 3, p0.w + p1.w + p2.w + p3.w);
        }
    }
}

// ---------------------------------------------------------------------------
// K2 single-pass score+pool: per (tile,b), 32-row tiles.
//   Wave w owns e-range; lane holds qk e-chunk for all 8 heads in regs
//   (32 VGPR, loaded once). Per 4-row sub-tile: dots -> wave allreduce ->
//   cross-wave finalize (512B LDS) -> outer product with the SAME kv regs.
//   Key read exactly once; PPpart plain stores; 8 ssum atomics/block.
//   PLAIN __launch_bounds__(256): the ",4" variant capped VGPR at 64 and
//   spilled ~50 regs/thread (R6: 120 MB phantom writes). Budget ~116 VGPR
//   fits the 4-waves/EU (<=128) occupancy tier naturally.
// grid (NT_, B_) = 1024 blocks, 256 thr, ~1 KB LDS.
// ---------------------------------------------------------------------------
__global__ __launch_bounds__(256) void k_scorepool(
        const float* __restrict__ key, const float* __restrict__ qk,
        const float* __restrict__ qb, float* __restrict__ PPpart,
        float* __restrict__ ssum)
{
    const int tile = blockIdx.x, b = blockIdx.y;
    const int t = threadIdx.x;
    const int w = t >> 6, l = t & 63;
    const int ei = (w << 6) + l;              // float4 index in [0,256)

    __shared__ __align__(16) float part[4][4][8];   // [wave][r][h], 512 B
    __shared__ __align__(16) float sfin[4][8];      // [r][h], 128 B

    const float scale = 0.08838834764831845f;  // 1/sqrt(128)
    const float* keyb = key + ((size_t)b * N_ + (size_t)tile * TR_) * E_;
    const float qbv = (t < 32) ? qb[b * 8 + (t & 7)] : 0.f;

    // qk fragments: 8 heads x float4 at this lane's e-chunk (read once)
    float4 qkr[8];
    #pragma unroll
    for (int h = 0; h < H_; ++h)
        qkr[h] = ((const float4*)(qk + (size_t)(b * 8 + h) * E_))[ei];

    float4 pacc[8];
    #pragma unroll
    for (int h = 0; h < 8; ++h) pacc[h] = make_float4(0.f, 0.f, 0.f, 0.f);

    float ts = 0.f;                           // finalize-thread accumulator

    float4 kv[4];
    #pragma unroll
    for (int r = 0; r < 4; ++r)
        kv[r] = ((const float4*)(keyb + (size_t)r * E_))[ei];

    for (int st = 0; st < 8; ++st) {
        // --- dots for this sub-tile's 4 rows
        #pragma unroll
        for (int r = 0; r < 4; ++r) {
            float p[8];
            #pragma unroll
            for (int h = 0; h < 8; ++h)
                p[h] = qkr[h].x * kv[r].x + qkr[h].y * kv[r].y
                     + qkr[h].z * kv[r].z + qkr[h].w * kv[r].w;
            #pragma unroll
            for (int off = 32; off; off >>= 1) {
                #pragma unroll
                for (int h = 0; h < 8; ++h)
                    p[h] += __shfl_xor(p[h], off);
            }
            if (l == 0) {
                *(float4*)&part[w][r][0] = make_float4(p[0], p[1], p[2], p[3]);
                *(float4*)&part[w][r][4] = make_float4(p[4], p[5], p[6], p[7]);
            }
        }
        // --- prefetch next sub-tile's rows (latency hidden by barriers)
        float4 kn[4];
        if (st < 7) {
            #pragma unroll
            for (int r = 0; r < 4; ++r)
                kn[r] = ((const float4*)(keyb
                            + (size_t)((st + 1) * 4 + r) * E_))[ei];
        }
        __syncthreads();
        // --- finalize s across the 4 waves (32 threads: r=t>>3, h=t&7)
        if (t < 32) {
            const int r = t >> 3, h = t & 7;
            float s = (part[0][r][h] + part[1][r][h]
                     + part[2][r][h] + part[3][r][h] + qbv) * scale;
            sfin[r][h] = s;
            ts += s;
        }
        __syncthreads();
        // --- outer product with the SAME kv registers
        #pragma unroll
        for (int r = 0; r < 4; ++r) {
            const float4 k4 = kv[r];
            const float4 sA = *(const float4*)&sfin[r][0];
            const float4 sB = *(const float4*)&sfin[r][4];
            pacc[0].x += sA.x * k4.x; pacc[0].y += sA.x * k4.y;
            pacc[0].z += sA.x * k4.z; pacc[0].w += sA.x * k4.w;
            pacc[1].x += sA.y * k4.x; pacc[1].y += sA.y * k4.y;
            pacc[1].z += sA.y * k4.z; pacc[1].w += sA.y * k4.w;
            pacc[2].x += sA.z * k4.x; pacc[2].y += sA.z * k4.y;
            pacc[2].z += sA.z * k4.z; pacc[2].w += sA.z * k4.w;
            pacc[3].x += sA.w * k4.x; pacc[3].y += sA.w * k4.y;
            pacc[3].z += sA.w * k4.z; pacc[3].w += sA.w * k4.w;
            pacc[4].x += sB.x * k4.x; pacc[4].y += sB.x * k4.y;
            pacc[4].z += sB.x * k4.z; pacc[4].w += sB.x * k4.w;
            pacc[5].x += sB.y * k4.x; pacc[5].y += sB.y * k4.y;
            pacc[5].z += sB.y * k4.z; pacc[5].w += sB.y * k4.w;
            pacc[6].x += sB.z * k4.x; pacc[6].y += sB.z * k4.y;
            pacc[6].z += sB.z * k4.z; pacc[6].w += sB.z * k4.w;
            pacc[7].x += sB.w * k4.x; pacc[7].y += sB.w * k4.y;
            pacc[7].z += sB.w * k4.z; pacc[7].w += sB.w * k4.w;
        }
        #pragma unroll
        for (int r = 0; r < 4; ++r) kv[r] = kn[r];
    }

    // --- ssum: finalize threads hold per-(r,h) tile sums; fold r, 8 atomics
    if (t < 32) {
        float v = ts;
        v += __shfl_xor(v, 8);
        v += __shfl_xor(v, 16);
        if (l < 8) atomicAdd(&ssum[b * 8 + l], v);
    }

    // --- PPpart write: one plain float4 store per (h, e-chunk)
    #pragma unroll
    for (int h = 0; h < 8; ++h) {
        ((float4*)(PPpart
            + (((size_t)(b * H_ + h)) * NT_ + tile) * E_))[ei] = pacc[h];
    }
}

// ---------------------------------------------------------------------------
// k_red: pooled[bh][e] = sum_{tl} PPpart[b,h,tl,e]. Done ONCE here so the 4
// dq-blocks of k_att don't each re-reduce the same 32 KB panel (R6 find:
// that was a 4x replay = 128 MB instead of 32 MB).
// grid (256 bh), 256 threads; per thread 32 independent 1KB-strided loads.
// ---------------------------------------------------------------------------
__global__ __launch_bounds__(256) void k_red(
        const float* __restrict__ PPpart, float* __restrict__ pooled)
{
    const int bh = blockIdx.x;
    const int t = threadIdx.x;
    const float4* pp = (const float4*)(PPpart + (size_t)bh * NT_ * E_);
    float4 s = make_float4(0.f, 0.f, 0.f, 0.f);
    #pragma unroll 8
    for (int tl = 0; tl < NT_; ++tl) {
        float4 v = pp[tl * 256 + t];
        s.x += v.x; s.y += v.y; s.z += v.z; s.w += v.w;
    }
    ((float4*)(pooled + (size_t)bh * E_))[t] = s;
}

// ---------------------------------------------------------------------------
// k_att: heavy Wv dots, d-partitioned across blocks.
//  attA[bh,d] = pooled[bh]·Wv_row(h*D+d);  attV[bh,d] = P2[b]·Wv_row(h*D+d)
// grid (4 dq, 256 bh), 256 threads -> 1024 blocks
// ---------------------------------------------------------------------------
__global__ __launch_bounds__(256) void k_att(
        const float* __restrict__ pooledG, const float* __restrict__ P2,
        const float* __restrict__ Wv,
        float* __restrict__ attA, float* __restrict__ attV)
{
    const int dq = blockIdx.x, bh = blockIdx.y;
    const int b = bh >> 3, h = bh & 7;
    const int t = threadIdx.x;
    const int l = t & 63, w = t >> 6;       // 4 waves
    const int rg = l >> 4, cl = l & 15;     // 4 row-groups x 16 lanes

    __shared__ __align__(16) float pooled[E_];
    __shared__ __align__(16) float pool2[E_];

    ((float4*)pooled)[t] = ((const float4*)(pooledG + (size_t)bh * E_))[t];
    ((float4*)pool2)[t]  = ((const float4*)(P2 + (size_t)b * E_))[t];
    __syncthreads();

    const float4* pooled4 = (const float4*)pooled;
    const float4* pool24  = (const float4*)pool2;
    #pragma unroll
    for (int p = 0; p < 2; ++p) {
        const int d = dq * 32 + p * 16 + w * 4 + rg;   // this block's 32 d's
        const float4* wvr = (const float4*)(Wv + (size_t)(h * D_ + d) * E_);
        float pA = 0.f, pV = 0.f;
        #pragma unroll 4
        for (int i = 0; i < 16; ++i) {
            float4 wv4 = wvr[cl + i * 16];
            float4 pa = pooled4[cl + i * 16];
            float4 pb = pool24[cl + i * 16];
            pA += wv4.x * pa.x + wv4.y * pa.y + wv4.z * pa.z + wv4.w * pa.w;
            pV += wv4.x * pb.x + wv4.y * pb.y + wv4.z * pb.z + wv4.w * pb.w;
        }
        #pragma unroll
        for (int off = 8; off; off >>= 1) {
            pA += __shfl_xor(pA, off);
            pV += __shfl_xor(pV, off);
        }
        if (cl == 0) {
            attA[(size_t)bh * D_ + d] = pA;
            attV[(size_t)bh * D_ + d] = pV;
        }
    }
}

// ---------------------------------------------------------------------------
// k_final (light epilogue). per (b,h), 128 threads (t = d)
//  att_d = attA + ssum*bv_d ; hv_m = relu(att·Wb_m + bb_m)
//  alphac_d = sigmoid(hv·Wl2_d + bl2_d) ; v2a_d = attV/cnt + bv_d
//  out = v1 * v2a * alphac
// ---------------------------------------------------------------------------
__global__ __launch_bounds__(128) void k_final(
        const float* __restrict__ attA, const float* __restrict__ attV,
        const float* __restrict__ ssumg, const int* __restrict__ mask,
        const float* __restrict__ bv, const float* __restrict__ Wb,
        const float* __restrict__ bb, const float* __restrict__ Wl2,
        const float* __restrict__ bl2, const float* __restrict__ value1,
        float* __restrict__ out)
{
    const int bh = blockIdx.x, b = bh >> 3, h = bh & 7;
    const int t = threadIdx.x;

    __shared__ float att[D_];
    __shared__ float hv[MID_];
    __shared__ float red2[2];
    __shared__ float cnt_s;

    int ci = 0;
    #pragma unroll
    for (int i = 0; i < 8; ++i) ci += mask[b * N_ + t + i * 128];
    float cf = (float)ci;
    #pragma unroll
    for (int off = 32; off; off >>= 1) cf += __shfl_down(cf, off);
    if ((t & 63) == 0) red2[t >> 6] = cf;

    const float ss = ssumg[bh];
    att[t] = attA[(size_t)bh * D_ + t] + ss * bv[h * D_ + t];
    __syncthreads();
    if (t == 0) cnt_s = red2[0] + red2[1];
    if (t < MID_) {
        float a = bb[t];
        #pragma unroll 4
        for (int d2 = 0; d2 < D_; ++d2) a += att[d2] * Wb[t * D_ + d2];
        hv[t] = fmaxf(a, 0.f);
    }
    __syncthreads();

    float z = bl2[t];
    #pragma unroll
    for (int m = 0; m < MID_; ++m) z += hv[m] * Wl2[t * MID_ + m];
    float alphac = 1.f / (1.f + expf(-z));
    const float bvd = bv[h * D_ + t];
    float v2a = attV[(size_t)bh * D_ + t] / cnt_s + bvd;
    out[(size_t)b * E_ + h * D_ + t] =
        value1[(size_t)b * E_ + h * D_ + t] * v2a * alphac;
}

// ---------------------------------------------------------------------------
extern "C" void kernel_launch(void* const* d_in, const int* in_sizes, int n_in,
                              void* d_out, int out_size, void* d_ws, size_t ws_size,
                              hipStream_t stream)
{
    const float* query  = (const float*)d_in[0];
    const float* key    = (const float*)d_in[1];
    const int*   mask   = (const int*)d_in[2];
    const float* value1 = (const float*)d_in[3];
    const float* value2 = (const float*)d_in[4];
    const float* Wq  = (const float*)d_in[5];
    const float* bq  = (const float*)d_in[6];
    const float* Wk  = (const float*)d_in[7];
    const float* bk  = (const float*)d_in[8];
    const float* Wv  = (const float*)d_in[9];
    const float* bv  = (const float*)d_in[10];
    const float* Wb  = (const float*)d_in[11];
    const float* bb  = (const float*)d_in[12];
    // d_in[13] = Wl, d_in[14] = bl: eliminated (softmax over identical values = mask/cnt)
    const float* Wl2 = (const float*)d_in[15];
    const float* bl2 = (const float*)d_in[16];
    float* out = (float*)d_out;

    // workspace layout (bytes), total ~36 MB
    char* ws = (char*)d_ws;
    const size_t SZ_PPP = (size_t)B_ * H_ * NT_ * E_ * 4;   // PPpart: 32 MB
    const size_t OFF_P2 = SZ_PPP;
    const size_t OFF_SS = OFF_P2 + (size_t)B_ * E_ * 4;     // P2: 128 KB
    const size_t OFF_QB = OFF_SS + 1024;                    // ssum: 1 KB
    const size_t OFF_QK = OFF_QB + 1024;                    // qb: 1 KB
    const size_t OFF_AA = OFF_QK + (size_t)B_ * H_ * E_ * 4;  // qk: 1 MB
    const size_t OFF_AV = OFF_AA + (size_t)B_ * H_ * D_ * 4;  // attA: 128 KB
    const size_t OFF_PL = OFF_AV + (size_t)B_ * H_ * D_ * 4;  // attV: 128 KB
    float* PPpart = (float*)(ws);
    float* P2   = (float*)(ws + OFF_P2);
    float* ssum = (float*)(ws + OFF_SS);
    float* qb   = (float*)(ws + OFF_QB);
    float* qk   = (float*)(ws + OFF_QK);
    float* attA = (float*)(ws + OFF_AA);
    float* attV = (float*)(ws + OFF_AV);
    float* pooled = (float*)(ws + OFF_PL);                  // pooled: 1 MB

    // zero only the atomic-accumulated region (P2 + ssum); PPpart is
    // fully overwritten by plain stores. stream-ordered, capture-safe
    hipMemsetAsync(ws + OFF_P2, 0, (size_t)B_ * E_ * 4 + 1024, stream);

    hipLaunchKernelGGL(k_pre, dim3(256 + NS2_ * B_), dim3(1024), 0, stream,
                       query, Wq, bq, Wk, bk, qk, qb, value2, mask, P2);
    hipLaunchKernelGGL(k_scorepool, dim3(NT_, B_), dim3(256), 0, stream,
                       key, qk, qb, PPpart, ssum);
    hipLaunchKernelGGL(k_red, dim3(B_ * H_), dim3(256), 0, stream,
                       PPpart, pooled);
    hipLaunchKernelGGL(k_att, dim3(4, B_ * H_), dim3(256), 0, stream,
                       pooled, P2, Wv, attA, attV);
    hipLaunchKernelGGL(k_final, dim3(B_ * H_), dim3(128), 0, stream,
                       attA, attV, ssum, mask, bv, Wb, bb, Wl2, bl2, value1, out);
}